// Round 10
// baseline (86.958 us; speedup 1.0000x reference)
//
#include <hip/hip_runtime.h>

#define NBINS 49
#define NCH   256
#define FH    256
#define FW    256
#define HWSZ  (FH * FW)
#define PLD   260            // padded LDS row stride (floats): 16B-aligned, bank-skewed
#define BCAP  25088          // bucket capacity (worst case: all bins of a batch in one slice)
#define NSL   8              // y-slices per batch (32 rows + 1 halo each)

typedef float f4 __attribute__((ext_vector_type(4)));

// ============================================================================
// R10: single-pass, bucketed, occupancy-doubled, decode-simplified.
// Ladder: R8 single-pass cut HBM 537->139MB but scan-bound (112us). R9
// bucketing killed the scan (-27us, matched prediction) -> 85us, still
// issue/latency-bound at 2 blocks/CU. R10: (a) 32-row slices -> LDS 34.3KB ->
// 4 blocks/CU x 512 thr = 32 waves/CU (max occupancy); (b) weights are
// provably in {0,0.25,0.5,1} (exact f32 products, validity-zeroed) -> encoded
// as 4x2-bit codes, decoded with 2 cndmask selects each -> per-entry decode
// chain halved. FMA expression and value set bit-identical to R1-R9 (absmax 0).
// PRE-COMMIT: if >= 70.8us, single-pass is exhausted -> revert to R7 two-pass.
// ============================================================================

__device__ __forceinline__ unsigned wq(float w) {   // exact quantize
    return w == 0.0f ? 0u : (w == 0.25f ? 1u : (w == 0.5f ? 2u : 3u));
}
__device__ __forceinline__ float wdq(unsigned bits) {  // exact dequant, branchless
    float hi = (bits & 1u) ? 1.0f  : 0.5f;
    float lo = (bits & 1u) ? 0.25f : 0.0f;
    return (bits & 2u) ? hi : lo;
}

// ---------------- pass 0: encode + bucket by (batch, yt>>5) ----------------
// code bits: [7:0]=xl [15:8]=yt [16]=dxr [17]=dyb [25:18]=4x2bit weights
// entry: .x = code, .y = (roi_local<<6)|bin
__global__ __launch_bounds__(64) void encode_geom(
    const float* __restrict__ boxes,   // (1024, 5)
    int*         __restrict__ cnts,    // (2*NSL)
    uint2*       __restrict__ buckets) // (2*NSL, BCAP)
{
    const int roi = blockIdx.x;
    const int tid = threadIdx.x;
    if (tid >= NBINS) return;
    const int b = roi >> 9;
    const float* bx = boxes + roi * 5;
    // --- exact f32 replication of reference geometry (absmax=0.0, R1-R9) ---
    float cx  = __fmul_rn(bx[0], 0.25f);
    float cy  = __fmul_rn(bx[1], 0.25f);
    float w   = __fmul_rn(bx[2], 0.25f);
    float h   = __fmul_rn(bx[3], 0.25f);
    float ang = __fmul_rn(bx[4], 0.017453292519943295f);
    float ca = (float)cos((double)ang);
    float sa = (float)sin((double)ang);
    float Sx = __fdiv_rn(w, 7.0f);
    float Sy = __fdiv_rn(h, 7.0f);
    const float dx = -3.5f, dy = -3.5f;
    float M00 = __fmul_rn(ca, Sx);
    float M01 = __fmul_rn(sa, Sy);
    float M02 = __fadd_rn(__fadd_rn(__fmul_rn(M00, dx), __fmul_rn(M01, dy)), cx);
    float nsa = -sa;
    float M10 = __fmul_rn(nsa, Sx);
    float M11 = __fmul_rn(ca, Sy);
    float M12 = __fadd_rn(__fadd_rn(__fmul_rn(M10, dx), __fmul_rn(M11, dy)), cy);

    int ph = tid / 7, pw = tid % 7;
    float minX = 1e30f, maxX = -1e30f, minY = 1e30f, maxY = -1e30f;
    #pragma unroll
    for (int o0 = 0; o0 < 2; ++o0) {
        #pragma unroll
        for (int o1 = 0; o1 < 2; ++o1) {
            float px = (float)(pw + o0);
            float py = (float)(ph + o1);
            float Xc = __fadd_rn(__fadd_rn(__fmul_rn(M00, px), __fmul_rn(M01, py)), M02);
            float Yc = __fadd_rn(__fadd_rn(__fmul_rn(M10, px), __fmul_rn(M11, py)), M12);
            minX = fminf(minX, Xc); maxX = fmaxf(maxX, Xc);
            minY = fminf(minY, Yc); maxY = fmaxf(maxY, Yc);
        }
    }
    float leftMost   = fmaxf(rintf(minX), 0.0f);
    float rightMost  = fminf(rintf(maxX), (float)(FW - 1));
    float topMost    = fmaxf(rintf(minY), 0.0f);
    float bottomMost = fminf(rintf(maxY), (float)(FH - 1));
    float bcx = __fmul_rn(__fadd_rn(leftMost, rightMost), 0.5f);
    float bcy = __fmul_rn(__fadd_rn(topMost, bottomMost), 0.5f);
    float fl = floorf(bcx), ft = floorf(bcy);
    int l   = (int)fl;
    int r   = (int)ceilf(bcx);
    int t   = (int)ft;
    int btm = (int)ceilf(bcy);
    float rx = __fsub_rn(bcx, fl);   // exactly 0.0 or 0.5
    float ry = __fsub_rn(bcy, ft);

    bool vl = (unsigned)l   < (unsigned)FW;
    bool vr = (unsigned)r   < (unsigned)FW;
    bool vt = (unsigned)t   < (unsigned)FH;
    bool vb = (unsigned)btm < (unsigned)FH;
    int xl = min(max(l, 0), FW - 1), xr = min(max(r, 0), FW - 1);
    int yt = min(max(t, 0), FH - 1), yb = min(max(btm, 0), FH - 1);
    // xr-xl, yb-yt in {0,1}: pre-clamp diff in {0,1}; clamping only collapses.

    // verbatim weight arithmetic -> values provably in {0, 0.25, 0.5, 1}
    float w_lt = (1.0f - rx) * (1.0f - ry);
    float w_rt = rx * (1.0f - ry);
    float w_rb = rx * ry;
    float w_lb = (1.0f - rx) * ry;
    float wlt = (vt && vl) ? w_lt : 0.0f;
    float wrt = (vt && vr) ? w_rt : 0.0f;
    float wrb = (vb && vr) ? w_rb : 0.0f;
    float wlb = (vb && vl) ? w_lb : 0.0f;
    unsigned wcode = wq(wlt) | (wq(wrt) << 2) | (wq(wrb) << 4) | (wq(wlb) << 6);

    unsigned code = (unsigned)xl
                  | ((unsigned)yt << 8)
                  | ((unsigned)(xr - xl) << 16)
                  | ((unsigned)(yb - yt) << 17)
                  | (wcode << 18);

    const int s = yt >> 5;               // slice 0..7
    const int roi_l = roi & 511;
    // wave-level aggregated append: ONE atomicAdd per slice per ROI-wave.
    #pragma unroll
    for (int ss = 0; ss < NSL; ++ss) {
        unsigned long long m = __ballot(s == ss);
        if (s == ss) {
            const int leader = (int)(__ffsll((long long)m) - 1);
            int base = 0;
            if (tid == leader)
                base = atomicAdd(&cnts[b * NSL + ss], __popcll(m));
            base = __shfl(base, leader);
            const int pos = __popcll(m & ((1ull << tid) - 1ull));
            uint2 e;
            e.x = code;
            e.y = ((unsigned)roi_l << 6) | (unsigned)tid;
            buckets[(size_t)(b * NSL + ss) * BCAP + base + pos] = e;
        }
    }
}

// ---------------- pass 1: pool, block = (batch, channel, y-slice) ----------------
// Loads rows [32s, 32s+32] of plane (b,c) into padded LDS (x read ONCE,
// coalesced f4; 34.3KB -> 4 blocks/CU, 32 waves/CU), then processes ONLY this
// slice's bucket entries: no skip-divergence, no div/mod, 2-cndmask weights.
__global__ __launch_bounds__(512) void rroi_pool_bucket(
    const float* __restrict__ x,       // (2, 256, 256, 256)
    const int*   __restrict__ cnts,    // (2*NSL)
    const uint2* __restrict__ buckets, // (2*NSL, BCAP)
    float*       __restrict__ out)     // (1024, 256, 7, 7)
{
    __shared__ float plane[33 * PLD];  // 34,320 B

    const int flat = blockIdx.x;       // 4096 = 2b * 256c * 8s
    const int s = flat & 7;
    const int c = (flat >> 3) & 255;
    const int b = flat >> 11;
    const int y0 = s * 32;
    const int nrows = (s == NSL - 1) ? 32 : 33;   // s7: rows 224..255 (yt=255 => dyb=0)
    const int nf4 = nrows * (FW / 4);

    // ---- fill: contiguous strip, coalesced f4 loads; padded LDS rows ----
    const f4* src4 = (const f4*)(x + ((size_t)(b * NCH + c) * HWSZ + (size_t)y0 * FW));
    f4* p4 = (f4*)plane;               // row stride PLD/4 = 65 f4 (16B-aligned)
    for (int j = threadIdx.x; j < nf4; j += 512) {
        const int row = j >> 6, c4 = j & 63;
        p4[row * (PLD / 4) + c4] = __builtin_nontemporal_load(src4 + j);
    }
    __syncthreads();

    // ---- process ONLY owned entries ----
    const int cnt = cnts[b * NSL + s];
    const uint2* bk = buckets + (size_t)(b * NSL + s) * BCAP;
    const size_t outBase = (size_t)b * 512 * (NCH * NBINS) + (size_t)c * NBINS;

    for (int i = threadIdx.x; i < cnt; i += 512) {
        const uint2 e = bk[i];                     // coalesced 8B
        const unsigned code = e.x;
        const unsigned rb_  = e.y;
        const int xl   = (int)(code & 255u);
        const int ytL  = (int)((code >> 8) & 255u) - y0;   // 0..31
        const int dxr  = (int)((code >> 16) & 1u);
        const int dyb  = (int)((code >> 17) & 1u);
        const unsigned wc = code >> 18;

        const int rbase = ytL * PLD + xl;
        const float lt = plane[rbase];
        const float rt = plane[rbase + dxr];
        const float lb = plane[rbase + dyb * PLD];
        const float rb = plane[rbase + dyb * PLD + dxr];

        const float wlt = wdq(wc & 3u);
        const float wrt = wdq((wc >> 2) & 3u);
        const float wrb = wdq((wc >> 4) & 3u);
        const float wlb = wdq((wc >> 6) & 3u);

        const float v = lt * wlt + rt * wrt + rb * wrb + lb * wlb;
        const unsigned roff = (rb_ >> 6) * (unsigned)(NCH * NBINS) + (rb_ & 63u);
        out[outBase + roff] = fmaxf(v, 0.0f);
    }
}

// ---------------- fallback: proven R0 single-pass kernel ----------------
__global__ __launch_bounds__(256) void rroi_pool_chw(
    const float* __restrict__ x, const float* __restrict__ boxes, float* __restrict__ out)
{
    __shared__ int   s_l[NBINS], s_r[NBINS], s_t[NBINS], s_b[NBINS];
    __shared__ float s_rx[NBINS], s_ry[NBINS];
    const int roi = blockIdx.x, tid = threadIdx.x, b = roi >> 9;
    if (tid < NBINS) {
        const float* bx = boxes + roi * 5;
        float cx  = __fmul_rn(bx[0], 0.25f);
        float cy  = __fmul_rn(bx[1], 0.25f);
        float w   = __fmul_rn(bx[2], 0.25f);
        float h   = __fmul_rn(bx[3], 0.25f);
        float ang = __fmul_rn(bx[4], 0.017453292519943295f);
        float ca = (float)cos((double)ang);
        float sa = (float)sin((double)ang);
        float Sx = __fdiv_rn(w, 7.0f);
        float Sy = __fdiv_rn(h, 7.0f);
        const float dx = -3.5f, dy = -3.5f;
        float M00 = __fmul_rn(ca, Sx);
        float M01 = __fmul_rn(sa, Sy);
        float M02 = __fadd_rn(__fadd_rn(__fmul_rn(M00, dx), __fmul_rn(M01, dy)), cx);
        float nsa = -sa;
        float M10 = __fmul_rn(nsa, Sx);
        float M11 = __fmul_rn(ca, Sy);
        float M12 = __fadd_rn(__fadd_rn(__fmul_rn(M10, dx), __fmul_rn(M11, dy)), cy);
        int ph = tid / 7, pw = tid % 7;
        float minX = 1e30f, maxX = -1e30f, minY = 1e30f, maxY = -1e30f;
        #pragma unroll
        for (int o0 = 0; o0 < 2; ++o0)
            #pragma unroll
            for (int o1 = 0; o1 < 2; ++o1) {
                float px = (float)(pw + o0);
                float py = (float)(ph + o1);
                float Xc = __fadd_rn(__fadd_rn(__fmul_rn(M00, px), __fmul_rn(M01, py)), M02);
                float Yc = __fadd_rn(__fadd_rn(__fmul_rn(M10, px), __fmul_rn(M11, py)), M12);
                minX = fminf(minX, Xc); maxX = fmaxf(maxX, Xc);
                minY = fminf(minY, Yc); maxY = fmaxf(maxY, Yc);
            }
        float leftMost   = fmaxf(rintf(minX), 0.0f);
        float rightMost  = fminf(rintf(maxX), (float)(FW - 1));
        float topMost    = fmaxf(rintf(minY), 0.0f);
        float bottomMost = fminf(rintf(maxY), (float)(FH - 1));
        float bcx = __fmul_rn(__fadd_rn(leftMost, rightMost), 0.5f);
        float bcy = __fmul_rn(__fadd_rn(topMost, bottomMost), 0.5f);
        float fl = floorf(bcx), ft = floorf(bcy);
        s_l[tid] = (int)fl;  s_r[tid] = (int)ceilf(bcx);
        s_t[tid] = (int)ft;  s_b[tid] = (int)ceilf(bcy);
        s_rx[tid] = __fsub_rn(bcx, fl);
        s_ry[tid] = __fsub_rn(bcy, ft);
    }
    __syncthreads();
    const float* featb = x + (size_t)b * NCH * HWSZ;
    float* outr = out + (size_t)roi * NCH * NBINS;
    for (int i = tid; i < NCH * NBINS; i += 256) {
        int c = i / NBINS, bin = i - c * NBINS;
        int l = s_l[bin], r = s_r[bin], t = s_t[bin], btm = s_b[bin];
        float rx = s_rx[bin], ry = s_ry[bin];
        const float* fc = featb + (size_t)c * HWSZ;
        bool vl = (unsigned)l < (unsigned)FW, vr = (unsigned)r < (unsigned)FW;
        bool vt = (unsigned)t < (unsigned)FH, vb = (unsigned)btm < (unsigned)FH;
        int lc = min(max(l, 0), FW - 1), rc = min(max(r, 0), FW - 1);
        int tc = min(max(t, 0), FH - 1), bc = min(max(btm, 0), FH - 1);
        float lt = (vt && vl) ? fc[tc * FW + lc] : 0.0f;
        float rt = (vt && vr) ? fc[tc * FW + rc] : 0.0f;
        float lb = (vb && vl) ? fc[bc * FW + lc] : 0.0f;
        float rb = (vb && vr) ? fc[bc * FW + rc] : 0.0f;
        float w_lt = (1.0f - rx) * (1.0f - ry);
        float w_rt = rx * (1.0f - ry);
        float w_rb = rx * ry;
        float w_lb = (1.0f - rx) * ry;
        float v = lt * w_lt + rt * w_rt + rb * w_rb + lb * w_lb;
        outr[i] = fmaxf(v, 0.0f);
    }
}

extern "C" void kernel_launch(void* const* d_in, const int* in_sizes, int n_in,
                              void* d_out, int out_size, void* d_ws, size_t ws_size,
                              hipStream_t stream) {
    const float* x     = (const float*)d_in[0];
    const float* boxes = (const float*)d_in[1];
    float* out = (float*)d_out;
    (void)in_sizes; (void)n_in; (void)out_size;

    // ws layout: [0,256) counters (16 ints), then 16 buckets (~3.2 MB)
    const size_t need = 256 + (size_t)2 * NSL * BCAP * sizeof(uint2);
    if (ws_size >= need) {
        int*   cnts    = (int*)d_ws;
        uint2* buckets = (uint2*)((char*)d_ws + 256);
        hipMemsetAsync(cnts, 0, 2 * NSL * sizeof(int), stream);
        encode_geom<<<dim3(1024), dim3(64), 0, stream>>>(boxes, cnts, buckets);
        rroi_pool_bucket<<<dim3(4096), dim3(512), 0, stream>>>(x, cnts, buckets, out);
    } else {
        rroi_pool_chw<<<dim3(1024), dim3(256), 0, stream>>>(x, boxes, out);
    }
}

// Round 11
// 70.854 us; speedup vs baseline: 1.2273x; 1.2273x over previous
//
#include <hip/hip_runtime.h>

#define NBINS 49
#define NCH   256
#define FH    256
#define FW    256
#define HWSZ  (FH * FW)

typedef float f4 __attribute__((ext_vector_type(4)));

// ============================================================================
// FINAL (R11 = R7 revert): two-pass transpose + NHWC pool, 70.8us proven.
// Session ledger:
//   R1  epilogue LDS-staging fix: 199.6 -> 71.0 (write amp 5.3x -> 1.0x)
//   R2  conditional gather:        -> 113.9 (gather must stay unconditional)
//   R3  bitmap write-predication:  ->  93.8 (occupancy 69%, atomic overhead)
//   R4  deeper load batching:      ->  70.9 (neutral: pool BW/latency floor)
//   R5  slab LLC reuse:            ->  81.4 (launch tails, no writeback win)
//   R6  pool||transpose overlap:   ->  84.1 (MLP loss + LLC contention)
//   R8  single-pass (no transpose):-> 112.5 (scan-bound despite 139MB HBM)
//   R9  + bucketing:               ->  84.9 (scan fixed, latency-bound)
//   R10 + occupancy/decode fixes:  ->  87.0 (occupancy wasn't the binder)
// Conclusion: issue structure beats raw traffic here; this two-pass pipeline
// is at its measured floor (transpose at 85-91% of achievable HBM ceiling,
// pool write fully coalesced, every alternative structure measured worse).
// ============================================================================

// ---------------- pass 1: transpose (B,C,H,W) -> (B,H*W,C) ----------------
#define TD 64
__global__ __launch_bounds__(256) void transpose_chw_hwc(
    const float* __restrict__ in,   // (2, 256, 65536)
    float* __restrict__ outT)       // (2, 65536, 256)
{
    __shared__ float tile[TD][TD + 1];
    const int t   = threadIdx.x;
    const int hw0 = blockIdx.x * TD;
    const int c0  = blockIdx.y * TD;
    const int bz  = blockIdx.z;
    const float* A = in   + (size_t)bz * NCH * HWSZ;
    float*       B = outT + (size_t)bz * HWSZ * NCH;

    // read: coalesced along HW (x streamed once -> nontemporal)
    const int hwq = (t & 15) * 4;   // 0..60
    const int cr  = t >> 4;         // 0..15
    #pragma unroll
    for (int k = 0; k < 4; ++k) {
        int c = cr + k * 16;
        f4 v = __builtin_nontemporal_load(
                   (const f4*)&A[(size_t)(c0 + c) * HWSZ + hw0 + hwq]);
        tile[c][hwq + 0] = v.x;
        tile[c][hwq + 1] = v.y;
        tile[c][hwq + 2] = v.z;
        tile[c][hwq + 3] = v.w;
    }
    __syncthreads();
    // write: coalesced along C (re-read by pool pass -> normal cached store)
    const int cq  = (t & 15) * 4;
    const int hwr = t >> 4;
    #pragma unroll
    for (int k = 0; k < 4; ++k) {
        int hw = hwr + k * 16;
        f4 v;
        v.x = tile[cq + 0][hw];
        v.y = tile[cq + 1][hw];
        v.z = tile[cq + 2][hw];
        v.w = tile[cq + 3][hw];
        *(f4*)&B[(size_t)(hw0 + hw) * NCH + c0 + cq] = v;
    }
}

// ---------------- pass 2: pool on NHWC, lane = channel ----------------
__global__ __launch_bounds__(256, 4) void rroi_pool_nhwc(
    const float* __restrict__ xt,     // (2, 65536, 256)
    const float* __restrict__ boxes,  // (1024, 5)
    float* __restrict__ out)          // (1024, 256, 7, 7)
{
    __shared__ int   s_oTL[NBINS], s_oTR[NBINS], s_oBL[NBINS], s_oBR[NBINS];
    __shared__ float s_wlt[NBINS], s_wrt[NBINS], s_wrb[NBINS], s_wlb[NBINS];
    __shared__ __align__(16) float s_stage[128 * NBINS];   // 25,088 B

    const int roi = blockIdx.x;
    const int tid = threadIdx.x;      // = channel
    const int b   = roi >> 9;

    if (tid < NBINS) {
        const float* bx = boxes + roi * 5;
        // --- exact f32 replication of reference geometry (absmax=0.0 verified) ---
        float cx  = __fmul_rn(bx[0], 0.25f);
        float cy  = __fmul_rn(bx[1], 0.25f);
        float w   = __fmul_rn(bx[2], 0.25f);
        float h   = __fmul_rn(bx[3], 0.25f);
        float ang = __fmul_rn(bx[4], 0.017453292519943295f);
        float ca = (float)cos((double)ang);
        float sa = (float)sin((double)ang);
        float Sx = __fdiv_rn(w, 7.0f);
        float Sy = __fdiv_rn(h, 7.0f);
        const float dx = -3.5f, dy = -3.5f;
        float M00 = __fmul_rn(ca, Sx);
        float M01 = __fmul_rn(sa, Sy);
        float M02 = __fadd_rn(__fadd_rn(__fmul_rn(M00, dx), __fmul_rn(M01, dy)), cx);
        float nsa = -sa;
        float M10 = __fmul_rn(nsa, Sx);
        float M11 = __fmul_rn(ca, Sy);
        float M12 = __fadd_rn(__fadd_rn(__fmul_rn(M10, dx), __fmul_rn(M11, dy)), cy);

        int ph = tid / 7, pw = tid % 7;
        float minX = 1e30f, maxX = -1e30f, minY = 1e30f, maxY = -1e30f;
        #pragma unroll
        for (int o0 = 0; o0 < 2; ++o0) {
            #pragma unroll
            for (int o1 = 0; o1 < 2; ++o1) {
                float px = (float)(pw + o0);
                float py = (float)(ph + o1);
                float Xc = __fadd_rn(__fadd_rn(__fmul_rn(M00, px), __fmul_rn(M01, py)), M02);
                float Yc = __fadd_rn(__fadd_rn(__fmul_rn(M10, px), __fmul_rn(M11, py)), M12);
                minX = fminf(minX, Xc); maxX = fmaxf(maxX, Xc);
                minY = fminf(minY, Yc); maxY = fmaxf(maxY, Yc);
            }
        }
        float leftMost   = fmaxf(rintf(minX), 0.0f);
        float rightMost  = fminf(rintf(maxX), (float)(FW - 1));
        float topMost    = fmaxf(rintf(minY), 0.0f);
        float bottomMost = fminf(rintf(maxY), (float)(FH - 1));
        float bcx = __fmul_rn(__fadd_rn(leftMost, rightMost), 0.5f);
        float bcy = __fmul_rn(__fadd_rn(topMost, bottomMost), 0.5f);
        float fl = floorf(bcx), ft = floorf(bcy);
        int l   = (int)fl;
        int r   = (int)ceilf(bcx);
        int t   = (int)ft;
        int btm = (int)ceilf(bcy);
        float rx = __fsub_rn(bcx, fl);   // exactly 0.0 or 0.5
        float ry = __fsub_rn(bcy, ft);

        bool vl = (unsigned)l   < (unsigned)FW;
        bool vr = (unsigned)r   < (unsigned)FW;
        bool vt = (unsigned)t   < (unsigned)FH;
        bool vb = (unsigned)btm < (unsigned)FH;
        int xl = min(max(l, 0), FW - 1), xr = min(max(r, 0), FW - 1);
        int yt = min(max(t, 0), FH - 1), yb = min(max(btm, 0), FH - 1);

        s_oTL[tid] = yt * FW + xl;
        s_oTR[tid] = yt * FW + xr;
        s_oBL[tid] = yb * FW + xl;
        s_oBR[tid] = yb * FW + xr;
        float w_lt = (1.0f - rx) * (1.0f - ry);
        float w_rt = rx * (1.0f - ry);
        float w_rb = rx * ry;
        float w_lb = (1.0f - rx) * ry;
        s_wlt[tid] = (vt && vl) ? w_lt : 0.0f;
        s_wrt[tid] = (vt && vr) ? w_rt : 0.0f;
        s_wrb[tid] = (vb && vr) ? w_rb : 0.0f;
        s_wlb[tid] = (vb && vl) ? w_lb : 0.0f;
    }
    __syncthreads();

    const float* fb = xt + (size_t)b * HWSZ * NCH;
    float p[NBINS];
    // deep-batched gather: 13 bins (52 loads) per group, all indices
    // compile-time after unroll (rule: no runtime-indexed arrays -> scratch).
    #pragma unroll
    for (int g = 0; g < NBINS; g += 13) {
        const int GN = (g + 13 <= NBINS) ? 13 : (NBINS - g);
        float lt[13], rt[13], lb[13], rb[13];
        #pragma unroll
        for (int k = 0; k < 13; ++k) {
            if (k < GN) {
                const int bin = g + k;
                // wave-uniform point offsets -> SGPRs (SALU addr, saddr loads)
                int oTL = __builtin_amdgcn_readfirstlane(s_oTL[bin]);
                int oTR = __builtin_amdgcn_readfirstlane(s_oTR[bin]);
                int oBL = __builtin_amdgcn_readfirstlane(s_oBL[bin]);
                int oBR = __builtin_amdgcn_readfirstlane(s_oBR[bin]);
                lt[k] = fb[(size_t)oTL * NCH + tid];   // 64 lanes -> 256B contiguous
                rt[k] = fb[(size_t)oTR * NCH + tid];
                lb[k] = fb[(size_t)oBL * NCH + tid];
                rb[k] = fb[(size_t)oBR * NCH + tid];
            }
        }
        #pragma unroll
        for (int k = 0; k < 13; ++k) {
            if (k < GN) {
                const int bin = g + k;
                float v = lt[k] * s_wlt[bin] + rt[k] * s_wrt[bin]
                        + rb[k] * s_wrb[bin] + lb[k] * s_wlb[bin];
                p[bin] = fmaxf(v, 0.0f);
            }
        }
    }

    // ---- coalesced epilogue: two 128-channel halves through LDS ----
    // per-ROI output block = 256*49 dwords, linear index c*49+bin.
    f4* out4 = (f4*)(out + (size_t)roi * NCH * NBINS);
    const f4* lds4 = (const f4*)s_stage;
    const int HV4 = 128 * NBINS / 4;  // 1568 f4 per half (25,088 B, 16B-aligned)

    if ((tid >> 7) == 0) {                         // waves 0,1: channels 0-127
        float* dst = s_stage + tid * NBINS;        // stride 49: odd -> conflict-free
        #pragma unroll
        for (int bin = 0; bin < NBINS; ++bin) dst[bin] = p[bin];
    }
    __syncthreads();
    for (int j = tid; j < HV4; j += 256)
        __builtin_nontemporal_store(lds4[j], &out4[j]);
    __syncthreads();
    if ((tid >> 7) == 1) {                         // waves 2,3: channels 128-255
        float* dst = s_stage + (tid & 127) * NBINS;
        #pragma unroll
        for (int bin = 0; bin < NBINS; ++bin) dst[bin] = p[bin];
    }
    __syncthreads();
    for (int j = tid; j < HV4; j += 256)
        __builtin_nontemporal_store(lds4[j], &out4[HV4 + j]);
}

// ---------------- fallback: proven R0 single-pass kernel ----------------
__global__ __launch_bounds__(256) void rroi_pool_chw(
    const float* __restrict__ x, const float* __restrict__ boxes, float* __restrict__ out)
{
    __shared__ int   s_l[NBINS], s_r[NBINS], s_t[NBINS], s_b[NBINS];
    __shared__ float s_rx[NBINS], s_ry[NBINS];
    const int roi = blockIdx.x, tid = threadIdx.x, b = roi >> 9;
    if (tid < NBINS) {
        const float* bx = boxes + roi * 5;
        float cx  = __fmul_rn(bx[0], 0.25f);
        float cy  = __fmul_rn(bx[1], 0.25f);
        float w   = __fmul_rn(bx[2], 0.25f);
        float h   = __fmul_rn(bx[3], 0.25f);
        float ang = __fmul_rn(bx[4], 0.017453292519943295f);
        float ca = (float)cos((double)ang);
        float sa = (float)sin((double)ang);
        float Sx = __fdiv_rn(w, 7.0f);
        float Sy = __fdiv_rn(h, 7.0f);
        const float dx = -3.5f, dy = -3.5f;
        float M00 = __fmul_rn(ca, Sx);
        float M01 = __fmul_rn(sa, Sy);
        float M02 = __fadd_rn(__fadd_rn(__fmul_rn(M00, dx), __fmul_rn(M01, dy)), cx);
        float nsa = -sa;
        float M10 = __fmul_rn(nsa, Sx);
        float M11 = __fmul_rn(ca, Sy);
        float M12 = __fadd_rn(__fadd_rn(__fmul_rn(M10, dx), __fmul_rn(M11, dy)), cy);
        int ph = tid / 7, pw = tid % 7;
        float minX = 1e30f, maxX = -1e30f, minY = 1e30f, maxY = -1e30f;
        #pragma unroll
        for (int o0 = 0; o0 < 2; ++o0)
            #pragma unroll
            for (int o1 = 0; o1 < 2; ++o1) {
                float px = (float)(pw + o0);
                float py = (float)(ph + o1);
                float Xc = __fadd_rn(__fadd_rn(__fmul_rn(M00, px), __fmul_rn(M01, py)), M02);
                float Yc = __fadd_rn(__fadd_rn(__fmul_rn(M10, px), __fmul_rn(M11, py)), M12);
                minX = fminf(minX, Xc); maxX = fmaxf(maxX, Xc);
                minY = fminf(minY, Yc); maxY = fmaxf(maxY, Yc);
            }
        float leftMost   = fmaxf(rintf(minX), 0.0f);
        float rightMost  = fminf(rintf(maxX), (float)(FW - 1));
        float topMost    = fmaxf(rintf(minY), 0.0f);
        float bottomMost = fminf(rintf(maxY), (float)(FH - 1));
        float bcx = __fmul_rn(__fadd_rn(leftMost, rightMost), 0.5f);
        float bcy = __fmul_rn(__fadd_rn(topMost, bottomMost), 0.5f);
        float fl = floorf(bcx), ft = floorf(bcy);
        s_l[tid] = (int)fl;  s_r[tid] = (int)ceilf(bcx);
        s_t[tid] = (int)ft;  s_b[tid] = (int)ceilf(bcy);
        s_rx[tid] = __fsub_rn(bcx, fl);
        s_ry[tid] = __fsub_rn(bcy, ft);
    }
    __syncthreads();
    const float* featb = x + (size_t)b * NCH * HWSZ;
    float* outr = out + (size_t)roi * NCH * NBINS;
    for (int i = tid; i < NCH * NBINS; i += 256) {
        int c = i / NBINS, bin = i - c * NBINS;
        int l = s_l[bin], r = s_r[bin], t = s_t[bin], btm = s_b[bin];
        float rx = s_rx[bin], ry = s_ry[bin];
        const float* fc = featb + (size_t)c * HWSZ;
        bool vl = (unsigned)l < (unsigned)FW, vr = (unsigned)r < (unsigned)FW;
        bool vt = (unsigned)t < (unsigned)FH, vb = (unsigned)btm < (unsigned)FH;
        int lc = min(max(l, 0), FW - 1), rc = min(max(r, 0), FW - 1);
        int tc = min(max(t, 0), FH - 1), bc = min(max(btm, 0), FH - 1);
        float lt = (vt && vl) ? fc[tc * FW + lc] : 0.0f;
        float rt = (vt && vr) ? fc[tc * FW + rc] : 0.0f;
        float lb = (vb && vl) ? fc[bc * FW + lc] : 0.0f;
        float rb = (vb && vr) ? fc[bc * FW + rc] : 0.0f;
        float w_lt = (1.0f - rx) * (1.0f - ry);
        float w_rt = rx * (1.0f - ry);
        float w_rb = rx * ry;
        float w_lb = (1.0f - rx) * ry;
        float v = lt * w_lt + rt * w_rt + rb * w_rb + lb * w_lb;
        outr[i] = fmaxf(v, 0.0f);
    }
}

extern "C" void kernel_launch(void* const* d_in, const int* in_sizes, int n_in,
                              void* d_out, int out_size, void* d_ws, size_t ws_size,
                              hipStream_t stream) {
    const float* x     = (const float*)d_in[0];
    const float* boxes = (const float*)d_in[1];
    float* out = (float*)d_out;
    (void)in_sizes; (void)n_in; (void)out_size;

    const size_t need = (size_t)2 * NCH * HWSZ * sizeof(float);  // 128 MB
    if (ws_size >= need) {
        float* xt = (float*)d_ws;
        transpose_chw_hwc<<<dim3(HWSZ / TD, NCH / TD, 2), dim3(256), 0, stream>>>(x, xt);
        rroi_pool_nhwc<<<dim3(1024), dim3(256), 0, stream>>>(xt, boxes, out);
    } else {
        rroi_pool_chw<<<dim3(1024), dim3(256), 0, stream>>>(x, boxes, out);
    }
}